// Round 1
// baseline (2859.666 us; speedup 1.0000x reference)
//
#include <hip/hip_runtime.h>
#include <stdint.h>

#define NV 50000
#define NE 10000
#define HD 256
#define NP 400000

typedef short short8 __attribute__((ext_vector_type(8)));
typedef float f32x4 __attribute__((ext_vector_type(4)));

__device__ __forceinline__ short f2bf(float f) {
    unsigned int u = __builtin_bit_cast(unsigned int, f);
    u += 0x7FFFu + ((u >> 16) & 1u);   // round-to-nearest-even
    return (short)(u >> 16);
}

// ---------------------------------------------------------------------------
// init: v_region = v * n_weight (row-broadcast), e_region = e
// ---------------------------------------------------------------------------
__global__ __launch_bounds__(256) void init_out(
    const float* __restrict__ v, const float* __restrict__ e,
    const float* __restrict__ nw, float* __restrict__ out)
{
    int i = blockIdx.x * 256 + threadIdx.x;          // float4 index
    const int nv4 = NV * (HD / 4);                   // 3,200,000
    const int ne4 = NE * (HD / 4);
    if (i < nv4) {
        float4 a = ((const float4*)v)[i];
        float w = nw[i >> 6];                        // row = i*4/256
        float4 o; o.x = a.x * w; o.y = a.y * w; o.z = a.z * w; o.w = a.w * w;
        ((float4*)out)[i] = o;
    } else if (i < nv4 + ne4) {
        ((float4*)out)[i] = ((const float4*)e)[i - nv4];
    }
}

// ---------------------------------------------------------------------------
// GEMM: out[i][j] = relu(sum_k A[i][k]*W[j][k] + bias[j]) * rowscale[i]
// A: [M][256] f32, W: [256][256] f32 row-major (output-dim major), K=N=256.
// bf16 MFMA 16x16x32. Block = 256 thr (4 waves), tile 64 rows x 64 cols.
// LDS: A-tile + W-tile as bf16, 16B chunks XOR-swizzled (chunk c at row r
// stored at c ^ (r&7)) -> conflict-free b128 reads/writes, exactly 64 KB.
// ---------------------------------------------------------------------------
__global__ __launch_bounds__(256) void gemm_rs(
    const float* __restrict__ A,
    const float* __restrict__ W,
    const float* __restrict__ bias,
    const float* __restrict__ rowscale,
    float* __restrict__ out,
    int M)
{
    __shared__ short As[64 * 256];
    __shared__ short Ws[64 * 256];
    const int tid  = threadIdx.x;
    const int row0 = blockIdx.y * 64;
    const int col0 = blockIdx.x * 64;

    // stage: 2048 chunks of 8 f32 -> 8 bf16 per array, 8 chunks/thread
#pragma unroll
    for (int it = 0; it < 8; ++it) {
        int cl = it * 256 + tid;        // [0,2048)
        int r  = cl >> 5;               // tile row 0..63
        int c  = cl & 31;               // chunk 0..31 (8 elems each)
        int gr = row0 + r; gr = gr < M ? gr : M - 1;   // clamp tail rows
        const float* asrc = A + (size_t)gr * HD + (c << 3);
        float4 a0 = *(const float4*)asrc;
        float4 a1 = *(const float4*)(asrc + 4);
        short8 ap;
        ap[0] = f2bf(a0.x); ap[1] = f2bf(a0.y); ap[2] = f2bf(a0.z); ap[3] = f2bf(a0.w);
        ap[4] = f2bf(a1.x); ap[5] = f2bf(a1.y); ap[6] = f2bf(a1.z); ap[7] = f2bf(a1.w);
        *(short8*)&As[(r << 8) + ((c ^ (r & 7)) << 3)] = ap;

        const float* wsrc = W + (size_t)(col0 + r) * HD + (c << 3);
        float4 w0 = *(const float4*)wsrc;
        float4 w1 = *(const float4*)(wsrc + 4);
        short8 wp;
        wp[0] = f2bf(w0.x); wp[1] = f2bf(w0.y); wp[2] = f2bf(w0.z); wp[3] = f2bf(w0.w);
        wp[4] = f2bf(w1.x); wp[5] = f2bf(w1.y); wp[6] = f2bf(w1.z); wp[7] = f2bf(w1.w);
        *(short8*)&Ws[(r << 8) + ((c ^ (r & 7)) << 3)] = wp;
    }
    __syncthreads();

    const int lane = tid & 63;
    const int wv   = tid >> 6;          // wave id: rows [wv*16, wv*16+16)
    const int m16  = lane & 15;
    const int quad = lane >> 4;
    const int arow = (wv << 4) + m16;

    f32x4 acc[4];
#pragma unroll
    for (int nt = 0; nt < 4; ++nt) acc[nt] = (f32x4){0.f, 0.f, 0.f, 0.f};

#pragma unroll
    for (int ks = 0; ks < 8; ++ks) {    // K = 8 * 32
        int c = (ks << 2) + quad;       // 16B chunk index along K
        short8 afr = *(const short8*)&As[(arow << 8) + ((c ^ (arow & 7)) << 3)];
#pragma unroll
        for (int nt = 0; nt < 4; ++nt) {
            int brow = (nt << 4) + m16;
            short8 bfr = *(const short8*)&Ws[(brow << 8) + ((c ^ (m16 & 7)) << 3)];
            acc[nt] = __builtin_amdgcn_mfma_f32_16x16x32_bf16(afr, bfr, acc[nt], 0, 0, 0);
        }
    }

    // epilogue: D layout col=lane&15, row=quad*4+reg
#pragma unroll
    for (int r = 0; r < 4; ++r) {
        int row = row0 + (wv << 4) + (quad << 2) + r;
        if (row < M) {
            float rs = rowscale[row];
#pragma unroll
            for (int nt = 0; nt < 4; ++nt) {
                int col = col0 + (nt << 4) + m16;
                float val = acc[nt][r] + bias[col];
                val = fmaxf(val, 0.0f) * rs;
                out[(size_t)row * HD + col] = val;
            }
        }
    }
}

// ---------------------------------------------------------------------------
// scatter: dst[dst_idx[p]] += msg[src_idx[p]] * regw[p]   (one wave per pair)
// ---------------------------------------------------------------------------
__global__ __launch_bounds__(256) void scatter_add(
    const float* __restrict__ msg,
    const int* __restrict__ src_idx,
    const int* __restrict__ dst_idx,
    const float* __restrict__ regw,
    float* __restrict__ dst)
{
    int p    = (blockIdx.x << 2) + (threadIdx.x >> 6);
    int lane = threadIdx.x & 63;
    int s = src_idx[p];
    int d = dst_idx[p];
    float w = regw[p];
    const float4 m = ((const float4*)(msg + (size_t)s * HD))[lane];
    float* drow = dst + (size_t)d * HD + (lane << 2);
    unsafeAtomicAdd(drow + 0, m.x * w);
    unsafeAtomicAdd(drow + 1, m.y * w);
    unsafeAtomicAdd(drow + 2, m.z * w);
    unsafeAtomicAdd(drow + 3, m.w * w);
}

// ---------------------------------------------------------------------------
// row_div: data[row][:] /= s[row]
// ---------------------------------------------------------------------------
__global__ __launch_bounds__(256) void row_div(
    float* __restrict__ data, const float* __restrict__ s, int nrows)
{
    int i = blockIdx.x * 256 + threadIdx.x;          // float4 index
    if (i >= nrows * (HD / 4)) return;
    float dv = s[i >> 6];
    float4 x = ((float4*)data)[i];
    x.x /= dv; x.y /= dv; x.z /= dv; x.w /= dv;
    ((float4*)data)[i] = x;
}

extern "C" void kernel_launch(void* const* d_in, const int* in_sizes, int n_in,
                              void* d_out, int out_size, void* d_ws, size_t ws_size,
                              hipStream_t stream) {
    const float* v   = (const float*)d_in[0];
    const float* e   = (const float*)d_in[1];
    const float* W1  = (const float*)d_in[2];
    const float* b1  = (const float*)d_in[3];
    const float* W2  = (const float*)d_in[4];
    const float* b2  = (const float*)d_in[5];
    const float* n_weight     = (const float*)d_in[6];
    const float* e_weight     = (const float*)d_in[7];
    const float* n_reg_weight = (const float*)d_in[8];
    const float* e_reg_weight = (const float*)d_in[9];
    const float* e_reg_sum    = (const float*)d_in[10];
    const float* n_reg_sum    = (const float*)d_in[11];
    const int* pairs_v = (const int*)d_in[12];
    const int* eidx    = (const int*)d_in[13];
    const int* pairs_e = (const int*)d_in[14];
    const int* vidx    = (const int*)d_in[15];

    float* out      = (float*)d_out;
    float* v_region = out;                         // [NV][256] -> v_out
    float* e_region = out + (size_t)NV * HD;       // [NE][256] -> e_out
    float* msg      = (float*)d_ws;                // scratch [max(NV,NE)][256] f32

    // v_region = v * n_weight ; e_region = e
    init_out<<<15000, 256, 0, stream>>>(v, e, n_weight, out);
    // msg = relu(v @ W1^T + b1) * n_weight
    gemm_rs<<<dim3(4, (NV + 63) / 64), 256, 0, stream>>>(v, W1, b1, n_weight, msg, NV);
    // e_region[eidx[p]] += msg[pairs_v[p]] * n_reg_weight[p]
    scatter_add<<<NP / 4, 256, 0, stream>>>(msg, pairs_v, eidx, n_reg_weight, e_region);
    // e_region /= e_reg_sum   (this is e_out)
    row_div<<<(NE * (HD / 4) + 255) / 256, 256, 0, stream>>>(e_region, e_reg_sum, NE);
    // msg = relu(e_out @ W2^T + b2) * e_weight
    gemm_rs<<<dim3(4, (NE + 63) / 64), 256, 0, stream>>>(e_region, W2, b2, e_weight, msg, NE);
    // v_region[vidx[p]] += msg[pairs_e[p]] * e_reg_weight[p]
    scatter_add<<<NP / 4, 256, 0, stream>>>(msg, pairs_e, vidx, e_reg_weight, v_region);
    // v_region /= n_reg_sum   (this is v_out)
    row_div<<<(NV * (HD / 4) + 255) / 256, 256, 0, stream>>>(v_region, n_reg_sum, NV);
}

// Round 2
// 476.875 us; speedup vs baseline: 5.9967x; 5.9967x over previous
//
#include <hip/hip_runtime.h>
#include <stdint.h>

#define NV 50000
#define NE 10000
#define HD 256
#define NP 400000

typedef short short8 __attribute__((ext_vector_type(8)));
typedef short short4v __attribute__((ext_vector_type(4)));
typedef float f32x4 __attribute__((ext_vector_type(4)));

__device__ __forceinline__ short f2bf(float f) {
    unsigned int u = __builtin_bit_cast(unsigned int, f);
    u += 0x7FFFu + ((u >> 16) & 1u);   // round-to-nearest-even
    return (short)(u >> 16);
}
__device__ __forceinline__ float bf2f(short s) {
    unsigned int u = ((unsigned int)(unsigned short)s) << 16;
    return __builtin_bit_cast(float, u);
}

// ---------------------------------------------------------------------------
// CSR build: histogram of destination indices
// ---------------------------------------------------------------------------
__global__ __launch_bounds__(256) void hist_kernel(
    const int* __restrict__ eidx, const int* __restrict__ vidx,
    int* __restrict__ cnt_e, int* __restrict__ cnt_v)
{
    int p = blockIdx.x * 256 + threadIdx.x;
    if (p < NP) {
        atomicAdd(&cnt_e[eidx[p]], 1);
        atomicAdd(&cnt_v[vidx[p]], 1);
    }
}

// single-block exclusive scan (n <= 1024*chunk), writes off[0..n] and cur=off
__global__ __launch_bounds__(1024) void scan_excl(
    const int* __restrict__ cnt, int* __restrict__ off, int* __restrict__ cur, int n)
{
    __shared__ int sums[1024];
    int t = threadIdx.x;
    int c = (n + 1023) >> 10;
    int lo = t * c;
    int hi = lo + c; if (hi > n) hi = n;
    int s = 0;
    for (int i = lo; i < hi; ++i) s += cnt[i];
    sums[t] = s;
    __syncthreads();
    for (int d = 1; d < 1024; d <<= 1) {
        int val = (t >= d) ? sums[t - d] : 0;
        __syncthreads();
        sums[t] += val;
        __syncthreads();
    }
    int run = (t == 0) ? 0 : sums[t - 1];
    for (int i = lo; i < hi; ++i) {
        off[i] = run; cur[i] = run;
        run += cnt[i];
    }
    if (lo < n && hi == n) off[n] = run;
}

// fill buckets: entry = (src_row, fp32 pair-weight)
__global__ __launch_bounds__(256) void fill_kernel(
    const int* __restrict__ eidx, const int* __restrict__ pairs_v, const float* __restrict__ nrw,
    const int* __restrict__ vidx, const int* __restrict__ pairs_e, const float* __restrict__ erw,
    int* __restrict__ cur_e, int* __restrict__ cur_v,
    int2* __restrict__ be, int2* __restrict__ bv)
{
    int p = blockIdx.x * 256 + threadIdx.x;
    if (p < NP) {
        int pe = atomicAdd(&cur_e[eidx[p]], 1);
        be[pe] = make_int2(pairs_v[p], __float_as_int(nrw[p]));
        int pv = atomicAdd(&cur_v[vidx[p]], 1);
        bv[pv] = make_int2(pairs_e[p], __float_as_int(erw[p]));
    }
}

// ---------------------------------------------------------------------------
// GEMM: out_bf16[i][j] = relu(sum_k A[i][k]*W[j][k] + bias[j]) * rowscale[i]
// bf16 MFMA 16x16x32, 64x64 tile, XOR-swizzled LDS (conflict-free b128).
// ---------------------------------------------------------------------------
__global__ __launch_bounds__(256) void gemm_rs(
    const float* __restrict__ A,
    const float* __restrict__ W,
    const float* __restrict__ bias,
    const float* __restrict__ rowscale,
    short* __restrict__ out,          // bf16
    int M)
{
    __shared__ short As[64 * 256];
    __shared__ short Ws[64 * 256];
    const int tid  = threadIdx.x;
    const int row0 = blockIdx.y * 64;
    const int col0 = blockIdx.x * 64;

#pragma unroll
    for (int it = 0; it < 8; ++it) {
        int cl = it * 256 + tid;
        int r  = cl >> 5;
        int c  = cl & 31;
        int gr = row0 + r; gr = gr < M ? gr : M - 1;
        const float* asrc = A + (size_t)gr * HD + (c << 3);
        float4 a0 = *(const float4*)asrc;
        float4 a1 = *(const float4*)(asrc + 4);
        short8 ap;
        ap[0] = f2bf(a0.x); ap[1] = f2bf(a0.y); ap[2] = f2bf(a0.z); ap[3] = f2bf(a0.w);
        ap[4] = f2bf(a1.x); ap[5] = f2bf(a1.y); ap[6] = f2bf(a1.z); ap[7] = f2bf(a1.w);
        *(short8*)&As[(r << 8) + ((c ^ (r & 7)) << 3)] = ap;

        const float* wsrc = W + (size_t)(col0 + r) * HD + (c << 3);
        float4 w0 = *(const float4*)wsrc;
        float4 w1 = *(const float4*)(wsrc + 4);
        short8 wp;
        wp[0] = f2bf(w0.x); wp[1] = f2bf(w0.y); wp[2] = f2bf(w0.z); wp[3] = f2bf(w0.w);
        wp[4] = f2bf(w1.x); wp[5] = f2bf(w1.y); wp[6] = f2bf(w1.z); wp[7] = f2bf(w1.w);
        *(short8*)&Ws[(r << 8) + ((c ^ (r & 7)) << 3)] = wp;
    }
    __syncthreads();

    const int lane = tid & 63;
    const int wv   = tid >> 6;
    const int m16  = lane & 15;
    const int quad = lane >> 4;
    const int arow = (wv << 4) + m16;

    f32x4 acc[4];
#pragma unroll
    for (int nt = 0; nt < 4; ++nt) acc[nt] = (f32x4){0.f, 0.f, 0.f, 0.f};

#pragma unroll
    for (int ks = 0; ks < 8; ++ks) {
        int c = (ks << 2) + quad;
        short8 afr = *(const short8*)&As[(arow << 8) + ((c ^ (arow & 7)) << 3)];
#pragma unroll
        for (int nt = 0; nt < 4; ++nt) {
            int brow = (nt << 4) + m16;
            short8 bfr = *(const short8*)&Ws[(brow << 8) + ((c ^ (m16 & 7)) << 3)];
            acc[nt] = __builtin_amdgcn_mfma_f32_16x16x32_bf16(afr, bfr, acc[nt], 0, 0, 0);
        }
    }

#pragma unroll
    for (int r = 0; r < 4; ++r) {
        int row = row0 + (wv << 4) + (quad << 2) + r;
        if (row < M) {
            float rs = rowscale[row];
#pragma unroll
            for (int nt = 0; nt < 4; ++nt) {
                int col = col0 + (nt << 4) + m16;
                float val = acc[nt][r] + bias[col];
                val = fmaxf(val, 0.0f) * rs;
                out[(size_t)row * HD + col] = f2bf(val);
            }
        }
    }
}

// ---------------------------------------------------------------------------
// gather_e: e_out[r] = (e[r] + sum_{i in bucket[r]} msg[src_i]*w_i) / reg_sum[r]
// one wave per row; lane handles 4 consecutive floats
// ---------------------------------------------------------------------------
__global__ __launch_bounds__(256) void gather_e(
    const short* __restrict__ msg,       // [NV][256] bf16
    const int2* __restrict__ bucket,
    const int* __restrict__ off,
    const float* __restrict__ e_in,
    const float* __restrict__ reg_sum,
    float* __restrict__ out)
{
    int r    = (blockIdx.x << 2) + (threadIdx.x >> 6);
    int lane = threadIdx.x & 63;
    float4 acc = ((const float4*)(e_in + (size_t)r * HD))[lane];
    int i = off[r], end = off[r + 1];
    for (; i + 2 <= end; i += 2) {
        int2 b0 = bucket[i];
        int2 b1 = bucket[i + 1];
        short4v m0 = *(const short4v*)(msg + ((size_t)b0.x << 8) + (lane << 2));
        short4v m1 = *(const short4v*)(msg + ((size_t)b1.x << 8) + (lane << 2));
        float w0 = __builtin_bit_cast(float, b0.y);
        float w1 = __builtin_bit_cast(float, b1.y);
        acc.x += bf2f(m0[0]) * w0; acc.y += bf2f(m0[1]) * w0;
        acc.z += bf2f(m0[2]) * w0; acc.w += bf2f(m0[3]) * w0;
        acc.x += bf2f(m1[0]) * w1; acc.y += bf2f(m1[1]) * w1;
        acc.z += bf2f(m1[2]) * w1; acc.w += bf2f(m1[3]) * w1;
    }
    if (i < end) {
        int2 b0 = bucket[i];
        short4v m0 = *(const short4v*)(msg + ((size_t)b0.x << 8) + (lane << 2));
        float w0 = __builtin_bit_cast(float, b0.y);
        acc.x += bf2f(m0[0]) * w0; acc.y += bf2f(m0[1]) * w0;
        acc.z += bf2f(m0[2]) * w0; acc.w += bf2f(m0[3]) * w0;
    }
    float inv = 1.0f / reg_sum[r];
    acc.x *= inv; acc.y *= inv; acc.z *= inv; acc.w *= inv;
    ((float4*)(out + (size_t)r * HD))[lane] = acc;
}

// ---------------------------------------------------------------------------
// gather_v: v_out[r] = (v[r]*n_w[r] + sum msg[src]*w) / reg_sum[r]
// ---------------------------------------------------------------------------
__global__ __launch_bounds__(256) void gather_v(
    const short* __restrict__ msg,       // [NE][256] bf16
    const int2* __restrict__ bucket,
    const int* __restrict__ off,
    const float* __restrict__ v_in,
    const float* __restrict__ n_w,
    const float* __restrict__ reg_sum,
    float* __restrict__ out)
{
    int r    = (blockIdx.x << 2) + (threadIdx.x >> 6);
    int lane = threadIdx.x & 63;
    float nw = n_w[r];
    float4 a = ((const float4*)(v_in + (size_t)r * HD))[lane];
    float4 acc; acc.x = a.x * nw; acc.y = a.y * nw; acc.z = a.z * nw; acc.w = a.w * nw;
    int i = off[r], end = off[r + 1];
    for (; i + 2 <= end; i += 2) {
        int2 b0 = bucket[i];
        int2 b1 = bucket[i + 1];
        short4v m0 = *(const short4v*)(msg + ((size_t)b0.x << 8) + (lane << 2));
        short4v m1 = *(const short4v*)(msg + ((size_t)b1.x << 8) + (lane << 2));
        float w0 = __builtin_bit_cast(float, b0.y);
        float w1 = __builtin_bit_cast(float, b1.y);
        acc.x += bf2f(m0[0]) * w0; acc.y += bf2f(m0[1]) * w0;
        acc.z += bf2f(m0[2]) * w0; acc.w += bf2f(m0[3]) * w0;
        acc.x += bf2f(m1[0]) * w1; acc.y += bf2f(m1[1]) * w1;
        acc.z += bf2f(m1[2]) * w1; acc.w += bf2f(m1[3]) * w1;
    }
    if (i < end) {
        int2 b0 = bucket[i];
        short4v m0 = *(const short4v*)(msg + ((size_t)b0.x << 8) + (lane << 2));
        float w0 = __builtin_bit_cast(float, b0.y);
        acc.x += bf2f(m0[0]) * w0; acc.y += bf2f(m0[1]) * w0;
        acc.z += bf2f(m0[2]) * w0; acc.w += bf2f(m0[3]) * w0;
    }
    float inv = 1.0f / reg_sum[r];
    acc.x *= inv; acc.y *= inv; acc.z *= inv; acc.w *= inv;
    ((float4*)(out + (size_t)r * HD))[lane] = acc;
}

extern "C" void kernel_launch(void* const* d_in, const int* in_sizes, int n_in,
                              void* d_out, int out_size, void* d_ws, size_t ws_size,
                              hipStream_t stream) {
    const float* v   = (const float*)d_in[0];
    const float* e   = (const float*)d_in[1];
    const float* W1  = (const float*)d_in[2];
    const float* b1  = (const float*)d_in[3];
    const float* W2  = (const float*)d_in[4];
    const float* b2  = (const float*)d_in[5];
    const float* n_weight     = (const float*)d_in[6];
    const float* e_weight     = (const float*)d_in[7];
    const float* n_reg_weight = (const float*)d_in[8];
    const float* e_reg_weight = (const float*)d_in[9];
    const float* e_reg_sum    = (const float*)d_in[10];
    const float* n_reg_sum    = (const float*)d_in[11];
    const int* pairs_v = (const int*)d_in[12];
    const int* eidx    = (const int*)d_in[13];
    const int* pairs_e = (const int*)d_in[14];
    const int* vidx    = (const int*)d_in[15];

    float* out      = (float*)d_out;
    float* v_region = out;
    float* e_region = out + (size_t)NV * HD;

    // workspace layout (all 256B-aligned); total ~32.7 MB
    char* ws = (char*)d_ws;
    size_t o = 0;
    short* msg      = (short*)(ws + o); o += (size_t)NV * HD * 2;       // 25.6 MB
    int2*  bucket_e = (int2*)(ws + o);  o += (size_t)NP * 8;            // 3.2 MB
    int2*  bucket_v = (int2*)(ws + o);  o += (size_t)NP * 8;            // 3.2 MB
    int*   off_e    = (int*)(ws + o);   o += ((NE + 1) * 4 + 255) & ~255ull;
    int*   cur_e    = (int*)(ws + o);   o += (NE * 4 + 255) & ~255ull;
    int*   off_v    = (int*)(ws + o);   o += ((NV + 1) * 4 + 255) & ~255ull;
    int*   cur_v    = (int*)(ws + o);   o += (NV * 4 + 255) & ~255ull;
    int*   cnt_e    = (int*)(ws + o);   o += (NE * 4 + 255) & ~255ull;
    int*   cnt_v    = (int*)(ws + o);   o += (NV * 4 + 255) & ~255ull;

    // CSR build
    hipMemsetAsync(cnt_e, 0, (size_t)(((NE * 4 + 255) & ~255ull) + NV * 4), stream);
    hist_kernel<<<(NP + 255) / 256, 256, 0, stream>>>(eidx, vidx, cnt_e, cnt_v);
    scan_excl<<<1, 1024, 0, stream>>>(cnt_e, off_e, cur_e, NE);
    scan_excl<<<1, 1024, 0, stream>>>(cnt_v, off_v, cur_v, NV);
    fill_kernel<<<(NP + 255) / 256, 256, 0, stream>>>(
        eidx, pairs_v, n_reg_weight, vidx, pairs_e, e_reg_weight,
        cur_e, cur_v, bucket_e, bucket_v);

    // msg = bf16( relu(v @ W1^T + b1) * n_weight )
    gemm_rs<<<dim3(4, (NV + 63) / 64), 256, 0, stream>>>(v, W1, b1, n_weight, msg, NV);
    // e_out = (e + gather(msg)) / e_reg_sum
    gather_e<<<NE / 4, 256, 0, stream>>>(msg, bucket_e, off_e, e, e_reg_sum, e_region);
    // msg = bf16( relu(e_out @ W2^T + b2) * e_weight )
    gemm_rs<<<dim3(4, (NE + 63) / 64), 256, 0, stream>>>(e_region, W2, b2, e_weight, msg, NE);
    // v_out = (v*n_weight + gather(msg)) / n_reg_sum
    gather_v<<<NV / 4, 256, 0, stream>>>(msg, bucket_v, off_v, v, n_weight, n_reg_sum, v_region);
}

// Round 3
// 373.608 us; speedup vs baseline: 7.6542x; 1.2764x over previous
//
#include <hip/hip_runtime.h>
#include <stdint.h>

#define NV 50000
#define NE 10000
#define HD 256
#define NP 400000

typedef short short8 __attribute__((ext_vector_type(8)));
typedef short short4v __attribute__((ext_vector_type(4)));
typedef float f32x4 __attribute__((ext_vector_type(4)));

__device__ __forceinline__ short f2bf(float f) {
    unsigned int u = __builtin_bit_cast(unsigned int, f);
    u += 0x7FFFu + ((u >> 16) & 1u);   // round-to-nearest-even
    return (short)(u >> 16);
}
__device__ __forceinline__ float bf2f(short s) {
    unsigned int u = ((unsigned int)(unsigned short)s) << 16;
    return __builtin_bit_cast(float, u);
}

// ---------------------------------------------------------------------------
// CSR build step 1: histogram of destination indices
// ---------------------------------------------------------------------------
__global__ __launch_bounds__(256) void hist_kernel(
    const int* __restrict__ eidx, const int* __restrict__ vidx,
    int* __restrict__ cnt_e, int* __restrict__ cnt_v)
{
    int p = blockIdx.x * 256 + threadIdx.x;
    if (p < NP) {
        atomicAdd(&cnt_e[eidx[p]], 1);
        atomicAdd(&cnt_v[vidx[p]], 1);
    }
}

// ---------------------------------------------------------------------------
// CSR build step 2: UNORDERED parallel range allocation (replaces the scan —
// bucket order across rows is irrelevant, only disjointness matters).
// off[r] = fetch_add(total, cnt[r]); cur[r] = off[r].
// ---------------------------------------------------------------------------
__global__ __launch_bounds__(256) void assign_kernel(
    const int* __restrict__ cnt_e, const int* __restrict__ cnt_v,
    int* __restrict__ off_e, int* __restrict__ cur_e,
    int* __restrict__ off_v, int* __restrict__ cur_v,
    int* __restrict__ tot)           // tot[0]=e-counter, tot[1]=v-counter
{
    int i = blockIdx.x * 256 + threadIdx.x;
    if (i < NE) {
        int base = atomicAdd(&tot[0], cnt_e[i]);
        off_e[i] = base; cur_e[i] = base;
    } else if (i < NE + NV) {
        int r = i - NE;
        int base = atomicAdd(&tot[1], cnt_v[r]);
        off_v[r] = base; cur_v[r] = base;
    }
}

// ---------------------------------------------------------------------------
// CSR build step 3: fill buckets: entry = (src_row, fp32 pair-weight)
// After this kernel, cur[r] == off[r] + cnt[r] == row end (used by gathers).
// ---------------------------------------------------------------------------
__global__ __launch_bounds__(256) void fill_kernel(
    const int* __restrict__ eidx, const int* __restrict__ pairs_v, const float* __restrict__ nrw,
    const int* __restrict__ vidx, const int* __restrict__ pairs_e, const float* __restrict__ erw,
    int* __restrict__ cur_e, int* __restrict__ cur_v,
    int2* __restrict__ be, int2* __restrict__ bv)
{
    int p = blockIdx.x * 256 + threadIdx.x;
    if (p < NP) {
        int pe = atomicAdd(&cur_e[eidx[p]], 1);
        be[pe] = make_int2(pairs_v[p], __float_as_int(nrw[p]));
        int pv = atomicAdd(&cur_v[vidx[p]], 1);
        bv[pv] = make_int2(pairs_e[p], __float_as_int(erw[p]));
    }
}

// ---------------------------------------------------------------------------
// GEMM: out_bf16[i][j] = relu(sum_k A[i][k]*W[j][k] + bias[j]) * rowscale[i]
// bf16 MFMA 16x16x32, 64x64 tile, XOR-swizzled LDS (conflict-free b128).
// ---------------------------------------------------------------------------
__global__ __launch_bounds__(256) void gemm_rs(
    const float* __restrict__ A,
    const float* __restrict__ W,
    const float* __restrict__ bias,
    const float* __restrict__ rowscale,
    short* __restrict__ out,          // bf16
    int M)
{
    __shared__ short As[64 * 256];
    __shared__ short Ws[64 * 256];
    const int tid  = threadIdx.x;
    const int row0 = blockIdx.y * 64;
    const int col0 = blockIdx.x * 64;

#pragma unroll
    for (int it = 0; it < 8; ++it) {
        int cl = it * 256 + tid;
        int r  = cl >> 5;
        int c  = cl & 31;
        int gr = row0 + r; gr = gr < M ? gr : M - 1;
        const float* asrc = A + (size_t)gr * HD + (c << 3);
        float4 a0 = *(const float4*)asrc;
        float4 a1 = *(const float4*)(asrc + 4);
        short8 ap;
        ap[0] = f2bf(a0.x); ap[1] = f2bf(a0.y); ap[2] = f2bf(a0.z); ap[3] = f2bf(a0.w);
        ap[4] = f2bf(a1.x); ap[5] = f2bf(a1.y); ap[6] = f2bf(a1.z); ap[7] = f2bf(a1.w);
        *(short8*)&As[(r << 8) + ((c ^ (r & 7)) << 3)] = ap;

        const float* wsrc = W + (size_t)(col0 + r) * HD + (c << 3);
        float4 w0 = *(const float4*)wsrc;
        float4 w1 = *(const float4*)(wsrc + 4);
        short8 wp;
        wp[0] = f2bf(w0.x); wp[1] = f2bf(w0.y); wp[2] = f2bf(w0.z); wp[3] = f2bf(w0.w);
        wp[4] = f2bf(w1.x); wp[5] = f2bf(w1.y); wp[6] = f2bf(w1.z); wp[7] = f2bf(w1.w);
        *(short8*)&Ws[(r << 8) + ((c ^ (r & 7)) << 3)] = wp;
    }
    __syncthreads();

    const int lane = tid & 63;
    const int wv   = tid >> 6;
    const int m16  = lane & 15;
    const int quad = lane >> 4;
    const int arow = (wv << 4) + m16;

    f32x4 acc[4];
#pragma unroll
    for (int nt = 0; nt < 4; ++nt) acc[nt] = (f32x4){0.f, 0.f, 0.f, 0.f};

#pragma unroll
    for (int ks = 0; ks < 8; ++ks) {
        int c = (ks << 2) + quad;
        short8 afr = *(const short8*)&As[(arow << 8) + ((c ^ (arow & 7)) << 3)];
#pragma unroll
        for (int nt = 0; nt < 4; ++nt) {
            int brow = (nt << 4) + m16;
            short8 bfr = *(const short8*)&Ws[(brow << 8) + ((c ^ (m16 & 7)) << 3)];
            acc[nt] = __builtin_amdgcn_mfma_f32_16x16x32_bf16(afr, bfr, acc[nt], 0, 0, 0);
        }
    }

#pragma unroll
    for (int r = 0; r < 4; ++r) {
        int row = row0 + (wv << 4) + (quad << 2) + r;
        if (row < M) {
            float rs = rowscale[row];
#pragma unroll
            for (int nt = 0; nt < 4; ++nt) {
                int col = col0 + (nt << 4) + m16;
                float val = acc[nt][r] + bias[col];
                val = fmaxf(val, 0.0f) * rs;
                out[(size_t)row * HD + col] = f2bf(val);
            }
        }
    }
}

// ---------------------------------------------------------------------------
// gather_e: e_out[r] = (e[r] + sum_{i in bucket[r]} msg[src_i]*w_i) / reg_sum[r]
// one wave per row; lane handles 4 consecutive floats
// ---------------------------------------------------------------------------
__global__ __launch_bounds__(256) void gather_e(
    const short* __restrict__ msg,       // [NV][256] bf16
    const int2* __restrict__ bucket,
    const int* __restrict__ off,
    const int* __restrict__ rend,        // cur[] after fill == row end
    const float* __restrict__ e_in,
    const float* __restrict__ reg_sum,
    float* __restrict__ out)
{
    int r    = (blockIdx.x << 2) + (threadIdx.x >> 6);
    int lane = threadIdx.x & 63;
    float4 acc = ((const float4*)(e_in + (size_t)r * HD))[lane];
    int i = off[r], end = rend[r];
    for (; i + 2 <= end; i += 2) {
        int2 b0 = bucket[i];
        int2 b1 = bucket[i + 1];
        short4v m0 = *(const short4v*)(msg + ((size_t)b0.x << 8) + (lane << 2));
        short4v m1 = *(const short4v*)(msg + ((size_t)b1.x << 8) + (lane << 2));
        float w0 = __builtin_bit_cast(float, b0.y);
        float w1 = __builtin_bit_cast(float, b1.y);
        acc.x += bf2f(m0[0]) * w0; acc.y += bf2f(m0[1]) * w0;
        acc.z += bf2f(m0[2]) * w0; acc.w += bf2f(m0[3]) * w0;
        acc.x += bf2f(m1[0]) * w1; acc.y += bf2f(m1[1]) * w1;
        acc.z += bf2f(m1[2]) * w1; acc.w += bf2f(m1[3]) * w1;
    }
    if (i < end) {
        int2 b0 = bucket[i];
        short4v m0 = *(const short4v*)(msg + ((size_t)b0.x << 8) + (lane << 2));
        float w0 = __builtin_bit_cast(float, b0.y);
        acc.x += bf2f(m0[0]) * w0; acc.y += bf2f(m0[1]) * w0;
        acc.z += bf2f(m0[2]) * w0; acc.w += bf2f(m0[3]) * w0;
    }
    float inv = 1.0f / reg_sum[r];
    acc.x *= inv; acc.y *= inv; acc.z *= inv; acc.w *= inv;
    ((float4*)(out + (size_t)r * HD))[lane] = acc;
}

// ---------------------------------------------------------------------------
// gather_v: v_out[r] = (v[r]*n_w[r] + sum msg[src]*w) / reg_sum[r]
// ---------------------------------------------------------------------------
__global__ __launch_bounds__(256) void gather_v(
    const short* __restrict__ msg,       // [NE][256] bf16
    const int2* __restrict__ bucket,
    const int* __restrict__ off,
    const int* __restrict__ rend,
    const float* __restrict__ v_in,
    const float* __restrict__ n_w,
    const float* __restrict__ reg_sum,
    float* __restrict__ out)
{
    int r    = (blockIdx.x << 2) + (threadIdx.x >> 6);
    int lane = threadIdx.x & 63;
    float nw = n_w[r];
    float4 a = ((const float4*)(v_in + (size_t)r * HD))[lane];
    float4 acc; acc.x = a.x * nw; acc.y = a.y * nw; acc.z = a.z * nw; acc.w = a.w * nw;
    int i = off[r], end = rend[r];
    for (; i + 2 <= end; i += 2) {
        int2 b0 = bucket[i];
        int2 b1 = bucket[i + 1];
        short4v m0 = *(const short4v*)(msg + ((size_t)b0.x << 8) + (lane << 2));
        short4v m1 = *(const short4v*)(msg + ((size_t)b1.x << 8) + (lane << 2));
        float w0 = __builtin_bit_cast(float, b0.y);
        float w1 = __builtin_bit_cast(float, b1.y);
        acc.x += bf2f(m0[0]) * w0; acc.y += bf2f(m0[1]) * w0;
        acc.z += bf2f(m0[2]) * w0; acc.w += bf2f(m0[3]) * w0;
        acc.x += bf2f(m1[0]) * w1; acc.y += bf2f(m1[1]) * w1;
        acc.z += bf2f(m1[2]) * w1; acc.w += bf2f(m1[3]) * w1;
    }
    if (i < end) {
        int2 b0 = bucket[i];
        short4v m0 = *(const short4v*)(msg + ((size_t)b0.x << 8) + (lane << 2));
        float w0 = __builtin_bit_cast(float, b0.y);
        acc.x += bf2f(m0[0]) * w0; acc.y += bf2f(m0[1]) * w0;
        acc.z += bf2f(m0[2]) * w0; acc.w += bf2f(m0[3]) * w0;
    }
    float inv = 1.0f / reg_sum[r];
    acc.x *= inv; acc.y *= inv; acc.z *= inv; acc.w *= inv;
    ((float4*)(out + (size_t)r * HD))[lane] = acc;
}

extern "C" void kernel_launch(void* const* d_in, const int* in_sizes, int n_in,
                              void* d_out, int out_size, void* d_ws, size_t ws_size,
                              hipStream_t stream) {
    const float* v   = (const float*)d_in[0];
    const float* e   = (const float*)d_in[1];
    const float* W1  = (const float*)d_in[2];
    const float* b1  = (const float*)d_in[3];
    const float* W2  = (const float*)d_in[4];
    const float* b2  = (const float*)d_in[5];
    const float* n_weight     = (const float*)d_in[6];
    const float* e_weight     = (const float*)d_in[7];
    const float* n_reg_weight = (const float*)d_in[8];
    const float* e_reg_weight = (const float*)d_in[9];
    const float* e_reg_sum    = (const float*)d_in[10];
    const float* n_reg_sum    = (const float*)d_in[11];
    const int* pairs_v = (const int*)d_in[12];
    const int* eidx    = (const int*)d_in[13];
    const int* pairs_e = (const int*)d_in[14];
    const int* vidx    = (const int*)d_in[15];

    float* out      = (float*)d_out;
    float* v_region = out;
    float* e_region = out + (size_t)NV * HD;

    // workspace layout; total ~33 MB
    char* ws = (char*)d_ws;
    size_t o = 0;
    short* msg      = (short*)(ws + o); o += (size_t)NV * HD * 2;       // 25.6 MB
    int2*  bucket_e = (int2*)(ws + o);  o += (size_t)NP * 8;            // 3.2 MB
    int2*  bucket_v = (int2*)(ws + o);  o += (size_t)NP * 8;            // 3.2 MB
    int*   off_e    = (int*)(ws + o);   o += (size_t)NE * 4;
    int*   cur_e    = (int*)(ws + o);   o += (size_t)NE * 4;
    int*   off_v    = (int*)(ws + o);   o += (size_t)NV * 4;
    int*   cur_v    = (int*)(ws + o);   o += (size_t)NV * 4;
    // zeroed region (one memset): cnt_e | cnt_v | tot[2]
    int*   cnt_e    = (int*)(ws + o);   o += (size_t)NE * 4;
    int*   cnt_v    = (int*)(ws + o);   o += (size_t)NV * 4;
    int*   tot      = (int*)(ws + o);   o += 2 * 4;

    // CSR build (order-free): hist -> parallel range alloc -> fill
    hipMemsetAsync(cnt_e, 0, (size_t)(NE + NV + 2) * 4, stream);
    hist_kernel<<<(NP + 255) / 256, 256, 0, stream>>>(eidx, vidx, cnt_e, cnt_v);
    assign_kernel<<<(NE + NV + 255) / 256, 256, 0, stream>>>(
        cnt_e, cnt_v, off_e, cur_e, off_v, cur_v, tot);
    fill_kernel<<<(NP + 255) / 256, 256, 0, stream>>>(
        eidx, pairs_v, n_reg_weight, vidx, pairs_e, e_reg_weight,
        cur_e, cur_v, bucket_e, bucket_v);

    // msg = bf16( relu(v @ W1^T + b1) * n_weight )
    gemm_rs<<<dim3(4, (NV + 63) / 64), 256, 0, stream>>>(v, W1, b1, n_weight, msg, NV);
    // e_out = (e + gather(msg)) / e_reg_sum
    gather_e<<<NE / 4, 256, 0, stream>>>(msg, bucket_e, off_e, cur_e, e, e_reg_sum, e_region);
    // msg = bf16( relu(e_out @ W2^T + b2) * e_weight )
    gemm_rs<<<dim3(4, (NE + 63) / 64), 256, 0, stream>>>(e_region, W2, b2, e_weight, msg, NE);
    // v_out = (v*n_weight + gather(msg)) / n_reg_sum
    gather_v<<<NV / 4, 256, 0, stream>>>(msg, bucket_v, off_v, cur_v, v, n_weight, n_reg_sum, v_region);
}

// Round 4
// 359.854 us; speedup vs baseline: 7.9467x; 1.0382x over previous
//
#include <hip/hip_runtime.h>
#include <stdint.h>

#define NV 50000
#define NE 10000
#define HD 256
#define NP 400000
#define VPAD 16384   // v-section offset in assign grid (wave-aligned past NE)

typedef short short8 __attribute__((ext_vector_type(8)));
typedef short short4v __attribute__((ext_vector_type(4)));
typedef float f32x4 __attribute__((ext_vector_type(4)));

__device__ __forceinline__ short f2bf(float f) {
    unsigned int u = __builtin_bit_cast(unsigned int, f);
    u += 0x7FFFu + ((u >> 16) & 1u);   // round-to-nearest-even
    return (short)(u >> 16);
}
__device__ __forceinline__ float bf2f(short s) {
    unsigned int u = ((unsigned int)(unsigned short)s) << 16;
    return __builtin_bit_cast(float, u);
}

// ---------------------------------------------------------------------------
// CSR step 1: histogram of destination indices
// ---------------------------------------------------------------------------
__global__ __launch_bounds__(256) void hist_kernel(
    const int* __restrict__ eidx, const int* __restrict__ vidx,
    int* __restrict__ cnt_e, int* __restrict__ cnt_v)
{
    int p = blockIdx.x * 256 + threadIdx.x;
    if (p < NP) {
        atomicAdd(&cnt_e[eidx[p]], 1);
        atomicAdd(&cnt_v[vidx[p]], 1);
    }
}

// ---------------------------------------------------------------------------
// CSR step 2: unordered range allocation, wave-aggregated (1 atomic per wave).
// Grid covers [0,VPAD) -> e rows (valid < NE), [VPAD, VPAD+NV) -> v rows.
// Waves never mix the two sections (VPAD is 64-aligned, NE < VPAD).
// ---------------------------------------------------------------------------
__global__ __launch_bounds__(256) void assign_kernel(
    const int* __restrict__ cnt_e, const int* __restrict__ cnt_v,
    int* __restrict__ off_e, int* __restrict__ cur_e,
    int* __restrict__ off_v, int* __restrict__ cur_v,
    int* __restrict__ tot)           // tot[0]=e-counter, tot[1]=v-counter
{
    int i = blockIdx.x * 256 + threadIdx.x;
    int lane = threadIdx.x & 63;
    bool is_e = i < VPAD;
    int idx = is_e ? i : (i - VPAD);
    bool valid = is_e ? (idx < NE) : (idx < NV);
    int cnt = valid ? (is_e ? cnt_e[idx] : cnt_v[idx]) : 0;
    // inclusive wave scan
    int x = cnt;
#pragma unroll
    for (int d = 1; d < 64; d <<= 1) {
        int y = __shfl_up(x, d);
        if (lane >= d) x += y;
    }
    int excl = x - cnt;
    int wsum = __shfl(x, 63);
    int base = 0;
    if (lane == 63 && wsum > 0) base = atomicAdd(&tot[is_e ? 0 : 1], wsum);
    base = __shfl(base, 63);
    if (valid) {
        int o = base + excl;
        if (is_e) { off_e[idx] = o; cur_e[idx] = o; }
        else      { off_v[idx] = o; cur_v[idx] = o; }
    }
}

// ---------------------------------------------------------------------------
// CSR step 3: fill perm buckets (4B pair index only).
// After this, cur[r] == off[r] + cnt[r] == row end.
// ---------------------------------------------------------------------------
__global__ __launch_bounds__(256) void fill_kernel(
    const int* __restrict__ eidx, const int* __restrict__ vidx,
    int* __restrict__ cur_e, int* __restrict__ cur_v,
    int* __restrict__ perm_e, int* __restrict__ perm_v)
{
    int p = blockIdx.x * 256 + threadIdx.x;
    if (p < NP) {
        int pe = atomicAdd(&cur_e[eidx[p]], 1);
        perm_e[pe] = p;
        int pv = atomicAdd(&cur_v[vidx[p]], 1);
        perm_v[pv] = p;
    }
}

// ---------------------------------------------------------------------------
// GEMM: out_bf16[i][j] = relu(sum_k A[i][k]*W[j][k] + bias[j]) * rowscale[i]
// Grid over 64-row tiles only; block loops over 4 column tiles (A staged ONCE,
// W tile restaged per iteration; W is L2-resident so re-reads are HBM-free).
// bf16 MFMA 16x16x32, XOR-swizzled LDS.
// ---------------------------------------------------------------------------
__global__ __launch_bounds__(256) void gemm_rs(
    const float* __restrict__ A,
    const float* __restrict__ W,
    const float* __restrict__ bias,
    const float* __restrict__ rowscale,
    short* __restrict__ out,          // bf16
    int M)
{
    __shared__ short As[64 * 256];
    __shared__ short Ws[64 * 256];
    const int tid  = threadIdx.x;
    const int row0 = blockIdx.x * 64;

    // stage A tile once: 2048 chunks of 8 f32 -> 8 bf16
#pragma unroll
    for (int it = 0; it < 8; ++it) {
        int cl = it * 256 + tid;
        int r  = cl >> 5;
        int c  = cl & 31;
        int gr = row0 + r; gr = gr < M ? gr : M - 1;
        const float* asrc = A + (size_t)gr * HD + (c << 3);
        float4 a0 = *(const float4*)asrc;
        float4 a1 = *(const float4*)(asrc + 4);
        short8 ap;
        ap[0] = f2bf(a0.x); ap[1] = f2bf(a0.y); ap[2] = f2bf(a0.z); ap[3] = f2bf(a0.w);
        ap[4] = f2bf(a1.x); ap[5] = f2bf(a1.y); ap[6] = f2bf(a1.z); ap[7] = f2bf(a1.w);
        *(short8*)&As[(r << 8) + ((c ^ (r & 7)) << 3)] = ap;
    }

    const int lane = tid & 63;
    const int wv   = tid >> 6;
    const int m16  = lane & 15;
    const int quad = lane >> 4;
    const int arow = (wv << 4) + m16;

    for (int ct = 0; ct < 4; ++ct) {
        __syncthreads();   // As staged (ct=0) / prior Ws reads done (ct>0)
        // stage W column tile ct
#pragma unroll
        for (int it = 0; it < 8; ++it) {
            int cl = it * 256 + tid;
            int r  = cl >> 5;
            int c  = cl & 31;
            const float* wsrc = W + (size_t)((ct << 6) + r) * HD + (c << 3);
            float4 w0 = *(const float4*)wsrc;
            float4 w1 = *(const float4*)(wsrc + 4);
            short8 wp;
            wp[0] = f2bf(w0.x); wp[1] = f2bf(w0.y); wp[2] = f2bf(w0.z); wp[3] = f2bf(w0.w);
            wp[4] = f2bf(w1.x); wp[5] = f2bf(w1.y); wp[6] = f2bf(w1.z); wp[7] = f2bf(w1.w);
            *(short8*)&Ws[(r << 8) + ((c ^ (r & 7)) << 3)] = wp;
        }
        __syncthreads();

        f32x4 acc[4];
#pragma unroll
        for (int nt = 0; nt < 4; ++nt) acc[nt] = (f32x4){0.f, 0.f, 0.f, 0.f};

#pragma unroll
        for (int ks = 0; ks < 8; ++ks) {
            int c = (ks << 2) + quad;
            short8 afr = *(const short8*)&As[(arow << 8) + ((c ^ (arow & 7)) << 3)];
#pragma unroll
            for (int nt = 0; nt < 4; ++nt) {
                int brow = (nt << 4) + m16;
                short8 bfr = *(const short8*)&Ws[(brow << 8) + ((c ^ (m16 & 7)) << 3)];
                acc[nt] = __builtin_amdgcn_mfma_f32_16x16x32_bf16(afr, bfr, acc[nt], 0, 0, 0);
            }
        }

#pragma unroll
        for (int r = 0; r < 4; ++r) {
            int row = row0 + (wv << 4) + (quad << 2) + r;
            if (row < M) {
                float rs = rowscale[row];
#pragma unroll
                for (int nt = 0; nt < 4; ++nt) {
                    int col = (ct << 6) + (nt << 4) + m16;
                    float val = acc[nt][r] + bias[col];
                    val = fmaxf(val, 0.0f) * rs;
                    out[(size_t)row * HD + col] = f2bf(val);
                }
            }
        }
    }
}

// ---------------------------------------------------------------------------
// gather: one wave per destination row; lanes cooperatively prefetch up to 64
// entries' metadata (perm -> pair idx -> src row + weight) in parallel, then
// broadcast per entry via shfl while streaming msg rows.
// out[r] = (base[r] + sum msg[src_i]*w_i) / reg_sum[r]
// ---------------------------------------------------------------------------
__device__ __forceinline__ void gather_core(
    const short* __restrict__ msg, const int* __restrict__ perm,
    const int* __restrict__ pairs, const float* __restrict__ regw,
    int i, int end, int lane, float4& acc)
{
    while (i < end) {
        int n = end - i; n = n < 64 ? n : 64;
        int src = 0; float w = 0.f;
        if (lane < n) {
            int p = perm[i + lane];
            src = pairs[p];
            w = regw[p];
        }
        int j = 0;
        for (; j + 2 <= n; j += 2) {
            int s0 = __shfl(src, j);     float w0 = __shfl(w, j);
            int s1 = __shfl(src, j + 1); float w1 = __shfl(w, j + 1);
            short4v m0 = *(const short4v*)(msg + ((size_t)s0 << 8) + (lane << 2));
            short4v m1 = *(const short4v*)(msg + ((size_t)s1 << 8) + (lane << 2));
            acc.x += bf2f(m0[0]) * w0; acc.y += bf2f(m0[1]) * w0;
            acc.z += bf2f(m0[2]) * w0; acc.w += bf2f(m0[3]) * w0;
            acc.x += bf2f(m1[0]) * w1; acc.y += bf2f(m1[1]) * w1;
            acc.z += bf2f(m1[2]) * w1; acc.w += bf2f(m1[3]) * w1;
        }
        if (j < n) {
            int s0 = __shfl(src, j); float w0 = __shfl(w, j);
            short4v m0 = *(const short4v*)(msg + ((size_t)s0 << 8) + (lane << 2));
            acc.x += bf2f(m0[0]) * w0; acc.y += bf2f(m0[1]) * w0;
            acc.z += bf2f(m0[2]) * w0; acc.w += bf2f(m0[3]) * w0;
        }
        i += n;
    }
}

__global__ __launch_bounds__(256) void gather_e(
    const short* __restrict__ msg,       // [NV][256] bf16
    const int* __restrict__ perm,
    const int* __restrict__ off, const int* __restrict__ rend,
    const int* __restrict__ pairs, const float* __restrict__ regw,
    const float* __restrict__ e_in, const float* __restrict__ reg_sum,
    float* __restrict__ out)
{
    int r    = (blockIdx.x << 2) + (threadIdx.x >> 6);
    int lane = threadIdx.x & 63;
    float4 acc = ((const float4*)(e_in + (size_t)r * HD))[lane];
    gather_core(msg, perm, pairs, regw, off[r], rend[r], lane, acc);
    float inv = 1.0f / reg_sum[r];
    acc.x *= inv; acc.y *= inv; acc.z *= inv; acc.w *= inv;
    ((float4*)(out + (size_t)r * HD))[lane] = acc;
}

__global__ __launch_bounds__(256) void gather_v(
    const short* __restrict__ msg,       // [NE][256] bf16
    const int* __restrict__ perm,
    const int* __restrict__ off, const int* __restrict__ rend,
    const int* __restrict__ pairs, const float* __restrict__ regw,
    const float* __restrict__ v_in, const float* __restrict__ n_w,
    const float* __restrict__ reg_sum, float* __restrict__ out)
{
    int r    = (blockIdx.x << 2) + (threadIdx.x >> 6);
    int lane = threadIdx.x & 63;
    float nw = n_w[r];
    float4 a = ((const float4*)(v_in + (size_t)r * HD))[lane];
    float4 acc; acc.x = a.x * nw; acc.y = a.y * nw; acc.z = a.z * nw; acc.w = a.w * nw;
    gather_core(msg, perm, pairs, regw, off[r], rend[r], lane, acc);
    float inv = 1.0f / reg_sum[r];
    acc.x *= inv; acc.y *= inv; acc.z *= inv; acc.w *= inv;
    ((float4*)(out + (size_t)r * HD))[lane] = acc;
}

extern "C" void kernel_launch(void* const* d_in, const int* in_sizes, int n_in,
                              void* d_out, int out_size, void* d_ws, size_t ws_size,
                              hipStream_t stream) {
    const float* v   = (const float*)d_in[0];
    const float* e   = (const float*)d_in[1];
    const float* W1  = (const float*)d_in[2];
    const float* b1  = (const float*)d_in[3];
    const float* W2  = (const float*)d_in[4];
    const float* b2  = (const float*)d_in[5];
    const float* n_weight     = (const float*)d_in[6];
    const float* e_weight     = (const float*)d_in[7];
    const float* n_reg_weight = (const float*)d_in[8];
    const float* e_reg_weight = (const float*)d_in[9];
    const float* e_reg_sum    = (const float*)d_in[10];
    const float* n_reg_sum    = (const float*)d_in[11];
    const int* pairs_v = (const int*)d_in[12];
    const int* eidx    = (const int*)d_in[13];
    const int* pairs_e = (const int*)d_in[14];
    const int* vidx    = (const int*)d_in[15];

    float* out      = (float*)d_out;
    float* v_region = out;
    float* e_region = out + (size_t)NV * HD;

    // workspace layout; total ~29.5 MB
    char* ws = (char*)d_ws;
    size_t o = 0;
    short* msg     = (short*)(ws + o); o += (size_t)NV * HD * 2;        // 25.6 MB
    int*   perm_e  = (int*)(ws + o);   o += (size_t)NP * 4;             // 1.6 MB
    int*   perm_v  = (int*)(ws + o);   o += (size_t)NP * 4;             // 1.6 MB
    int*   off_e   = (int*)(ws + o);   o += (size_t)NE * 4;
    int*   cur_e   = (int*)(ws + o);   o += (size_t)NE * 4;
    int*   off_v   = (int*)(ws + o);   o += (size_t)NV * 4;
    int*   cur_v   = (int*)(ws + o);   o += (size_t)NV * 4;
    // zeroed region (one memset): cnt_e | cnt_v | tot[2]
    int*   cnt_e   = (int*)(ws + o);   o += (size_t)NE * 4;
    int*   cnt_v   = (int*)(ws + o);   o += (size_t)NV * 4;
    int*   tot     = (int*)(ws + o);   o += 2 * 4;

    // CSR build (order-free): hist -> wave-aggregated range alloc -> perm fill
    hipMemsetAsync(cnt_e, 0, (size_t)(NE + NV + 2) * 4, stream);
    hist_kernel<<<(NP + 255) / 256, 256, 0, stream>>>(eidx, vidx, cnt_e, cnt_v);
    assign_kernel<<<(VPAD + NV + 255) / 256, 256, 0, stream>>>(
        cnt_e, cnt_v, off_e, cur_e, off_v, cur_v, tot);
    fill_kernel<<<(NP + 255) / 256, 256, 0, stream>>>(
        eidx, vidx, cur_e, cur_v, perm_e, perm_v);

    // msg = bf16( relu(v @ W1^T + b1) * n_weight )
    gemm_rs<<<(NV + 63) / 64, 256, 0, stream>>>(v, W1, b1, n_weight, msg, NV);
    // e_out = (e + gather(msg)) / e_reg_sum
    gather_e<<<NE / 4, 256, 0, stream>>>(msg, perm_e, off_e, cur_e,
                                         pairs_v, n_reg_weight, e, e_reg_sum, e_region);
    // msg = bf16( relu(e_out @ W2^T + b2) * e_weight )
    gemm_rs<<<(NE + 63) / 64, 256, 0, stream>>>(e_region, W2, b2, e_weight, msg, NE);
    // v_out = (v*n_weight + gather(msg)) / n_reg_sum
    gather_v<<<NV / 4, 256, 0, stream>>>(msg, perm_v, off_v, cur_v,
                                         pairs_e, e_reg_weight, v, n_weight, n_reg_sum, v_region);
}

// Round 5
// 355.421 us; speedup vs baseline: 8.0459x; 1.0125x over previous
//
#include <hip/hip_runtime.h>
#include <stdint.h>

#define NV 50000
#define NE 10000
#define HD 256
#define NP 400000
#define VPAD 16384   // v-section offset in assign grid (wave-aligned past NE)

#define PREP_VBLK 6250                 // v convert: 12.8M elems / 2048 per block
#define PREP_WBLK 64                   // W1+W2: 131072 elems / 2048
#define PREP_HBLK ((NP + 255) / 256)   // histogram blocks

typedef short short8 __attribute__((ext_vector_type(8)));
typedef short short4v __attribute__((ext_vector_type(4)));
typedef float f32x4 __attribute__((ext_vector_type(4)));

__device__ __forceinline__ short f2bf(float f) {
    unsigned int u = __builtin_bit_cast(unsigned int, f);
    u += 0x7FFFu + ((u >> 16) & 1u);   // round-to-nearest-even
    return (short)(u >> 16);
}
__device__ __forceinline__ float bf2f(short s) {
    unsigned int u = ((unsigned int)(unsigned short)s) << 16;
    return __builtin_bit_cast(float, u);
}

// ---------------------------------------------------------------------------
// prep: fused (v -> bf16) + (W1,W2 -> bf16) + destination histogram.
// Convert blocks are BW-bound, hist blocks are atomic-bound -> they overlap.
// ---------------------------------------------------------------------------
__global__ __launch_bounds__(256) void prep_kernel(
    const float* __restrict__ v, const float* __restrict__ W1, const float* __restrict__ W2,
    const int* __restrict__ eidx, const int* __restrict__ vidx,
    short* __restrict__ v_bf, short* __restrict__ W_bf,    // W_bf: [2*256*256]
    int* __restrict__ cnt_e, int* __restrict__ cnt_v, int conv_v)
{
    int b = blockIdx.x;
    int tid = threadIdx.x;
    if (b < PREP_VBLK) {
        if (!conv_v) return;
        size_t i = (size_t)b * 2048 + (size_t)tid * 8;
        float4 a0 = *(const float4*)(v + i);
        float4 a1 = *(const float4*)(v + i + 4);
        short8 s;
        s[0] = f2bf(a0.x); s[1] = f2bf(a0.y); s[2] = f2bf(a0.z); s[3] = f2bf(a0.w);
        s[4] = f2bf(a1.x); s[5] = f2bf(a1.y); s[6] = f2bf(a1.z); s[7] = f2bf(a1.w);
        *(short8*)(v_bf + i) = s;
    } else if (b < PREP_VBLK + PREP_WBLK) {
        size_t i = (size_t)(b - PREP_VBLK) * 2048 + (size_t)tid * 8;
        const float* src = (i < 65536) ? (W1 + i) : (W2 + (i - 65536));
        float4 a0 = *(const float4*)src;
        float4 a1 = *(const float4*)(src + 4);
        short8 s;
        s[0] = f2bf(a0.x); s[1] = f2bf(a0.y); s[2] = f2bf(a0.z); s[3] = f2bf(a0.w);
        s[4] = f2bf(a1.x); s[5] = f2bf(a1.y); s[6] = f2bf(a1.z); s[7] = f2bf(a1.w);
        *(short8*)(W_bf + i) = s;
    } else {
        int p = (b - PREP_VBLK - PREP_WBLK) * 256 + tid;
        if (p < NP) {
            atomicAdd(&cnt_e[eidx[p]], 1);
            atomicAdd(&cnt_v[vidx[p]], 1);
        }
    }
}

// ---------------------------------------------------------------------------
// CSR step 2: unordered range allocation, wave-aggregated (1 atomic per wave).
// ---------------------------------------------------------------------------
__global__ __launch_bounds__(256) void assign_kernel(
    const int* __restrict__ cnt_e, const int* __restrict__ cnt_v,
    int* __restrict__ off_e, int* __restrict__ cur_e,
    int* __restrict__ off_v, int* __restrict__ cur_v,
    int* __restrict__ tot)
{
    int i = blockIdx.x * 256 + threadIdx.x;
    int lane = threadIdx.x & 63;
    bool is_e = i < VPAD;
    int idx = is_e ? i : (i - VPAD);
    bool valid = is_e ? (idx < NE) : (idx < NV);
    int cnt = valid ? (is_e ? cnt_e[idx] : cnt_v[idx]) : 0;
    int x = cnt;
#pragma unroll
    for (int d = 1; d < 64; d <<= 1) {
        int y = __shfl_up(x, d);
        if (lane >= d) x += y;
    }
    int excl = x - cnt;
    int wsum = __shfl(x, 63);
    int base = 0;
    if (lane == 63 && wsum > 0) base = atomicAdd(&tot[is_e ? 0 : 1], wsum);
    base = __shfl(base, 63);
    if (valid) {
        int o = base + excl;
        if (is_e) { off_e[idx] = o; cur_e[idx] = o; }
        else      { off_v[idx] = o; cur_v[idx] = o; }
    }
}

// ---------------------------------------------------------------------------
// CSR step 3: fill perm buckets (4B pair index). After: cur[r] == row end.
// ---------------------------------------------------------------------------
__global__ __launch_bounds__(256) void fill_kernel(
    const int* __restrict__ eidx, const int* __restrict__ vidx,
    int* __restrict__ cur_e, int* __restrict__ cur_v,
    int* __restrict__ perm_e, int* __restrict__ perm_v)
{
    int p = blockIdx.x * 256 + threadIdx.x;
    if (p < NP) {
        int pe = atomicAdd(&cur_e[eidx[p]], 1);
        perm_e[pe] = p;
        int pv = atomicAdd(&cur_v[vidx[p]], 1);
        perm_v[pv] = p;
    }
}

// ---------------------------------------------------------------------------
// GEMM: out_bf16[i][j] = relu(sum_k A[i][k]*W[j][k] + bias[j]) * rowscale[i]
// A: [M][256] f32 or bf16 (a_bf flag); W: [256][256] bf16 row-major.
// Grid over 64-row tiles; block loops 4 column tiles. bf16 MFMA 16x16x32,
// XOR-swizzled LDS; staging is pure b128 copy when a_bf=1 (no VALU repack).
// ---------------------------------------------------------------------------
__global__ __launch_bounds__(256) void gemm_rs(
    const void* __restrict__ Av, int a_bf,
    const short* __restrict__ Wb,
    const float* __restrict__ bias,
    const float* __restrict__ rowscale,
    short* __restrict__ out,          // bf16
    int M)
{
    __shared__ short As[64 * 256];
    __shared__ short Ws[64 * 256];
    const int tid  = threadIdx.x;
    const int row0 = blockIdx.x * 64;

    // stage A tile once
#pragma unroll
    for (int it = 0; it < 8; ++it) {
        int cl = it * 256 + tid;
        int r  = cl >> 5;
        int c  = cl & 31;
        int gr = row0 + r; gr = gr < M ? gr : M - 1;
        short8 ap;
        if (a_bf) {
            ap = *(const short8*)((const short*)Av + (size_t)gr * HD + (c << 3));
        } else {
            const float* asrc = (const float*)Av + (size_t)gr * HD + (c << 3);
            float4 a0 = *(const float4*)asrc;
            float4 a1 = *(const float4*)(asrc + 4);
            ap[0] = f2bf(a0.x); ap[1] = f2bf(a0.y); ap[2] = f2bf(a0.z); ap[3] = f2bf(a0.w);
            ap[4] = f2bf(a1.x); ap[5] = f2bf(a1.y); ap[6] = f2bf(a1.z); ap[7] = f2bf(a1.w);
        }
        *(short8*)&As[(r << 8) + ((c ^ (r & 7)) << 3)] = ap;
    }

    const int lane = tid & 63;
    const int wv   = tid >> 6;
    const int m16  = lane & 15;
    const int quad = lane >> 4;
    const int arow = (wv << 4) + m16;

    for (int ct = 0; ct < 4; ++ct) {
        __syncthreads();   // As staged (ct=0) / prior Ws fragment reads done (ct>0)
        // stage W column tile ct (bf16 -> straight swizzled copy)
#pragma unroll
        for (int it = 0; it < 8; ++it) {
            int cl = it * 256 + tid;
            int r  = cl >> 5;
            int c  = cl & 31;
            short8 wp = *(const short8*)(Wb + (size_t)((ct << 6) + r) * HD + (c << 3));
            *(short8*)&Ws[(r << 8) + ((c ^ (r & 7)) << 3)] = wp;
        }
        __syncthreads();

        f32x4 acc[4];
#pragma unroll
        for (int nt = 0; nt < 4; ++nt) acc[nt] = (f32x4){0.f, 0.f, 0.f, 0.f};

#pragma unroll
        for (int ks = 0; ks < 8; ++ks) {
            int c = (ks << 2) + quad;
            short8 afr = *(const short8*)&As[(arow << 8) + ((c ^ (arow & 7)) << 3)];
#pragma unroll
            for (int nt = 0; nt < 4; ++nt) {
                int brow = (nt << 4) + m16;
                short8 bfr = *(const short8*)&Ws[(brow << 8) + ((c ^ (m16 & 7)) << 3)];
                acc[nt] = __builtin_amdgcn_mfma_f32_16x16x32_bf16(afr, bfr, acc[nt], 0, 0, 0);
            }
        }

#pragma unroll
        for (int r = 0; r < 4; ++r) {
            int row = row0 + (wv << 4) + (quad << 2) + r;
            if (row < M) {
                float rs = rowscale[row];
#pragma unroll
                for (int nt = 0; nt < 4; ++nt) {
                    int col = (ct << 6) + (nt << 4) + m16;
                    float val = acc[nt][r] + bias[col];
                    val = fmaxf(val, 0.0f) * rs;
                    out[(size_t)row * HD + col] = f2bf(val);
                }
            }
        }
    }
}

// ---------------------------------------------------------------------------
// gather core: lanes cooperatively prefetch up to 64 entries' metadata,
// broadcast via shfl; msg-row loads unrolled x4 for MLP.
// ---------------------------------------------------------------------------
__device__ __forceinline__ void gather_core(
    const short* __restrict__ msg, const int* __restrict__ perm,
    const int* __restrict__ pairs, const float* __restrict__ regw,
    int i, int end, int lane, float4& acc)
{
    while (i < end) {
        int n = end - i; n = n < 64 ? n : 64;
        int src = 0; float w = 0.f;
        if (lane < n) {
            int p = perm[i + lane];
            src = pairs[p];
            w = regw[p];
        }
        int j = 0;
        for (; j + 4 <= n; j += 4) {
            int   s0 = __shfl(src, j),     s1 = __shfl(src, j + 1);
            int   s2 = __shfl(src, j + 2), s3 = __shfl(src, j + 3);
            float w0 = __shfl(w, j),       w1 = __shfl(w, j + 1);
            float w2 = __shfl(w, j + 2),   w3 = __shfl(w, j + 3);
            short4v m0 = *(const short4v*)(msg + ((size_t)s0 << 8) + (lane << 2));
            short4v m1 = *(const short4v*)(msg + ((size_t)s1 << 8) + (lane << 2));
            short4v m2 = *(const short4v*)(msg + ((size_t)s2 << 8) + (lane << 2));
            short4v m3 = *(const short4v*)(msg + ((size_t)s3 << 8) + (lane << 2));
            acc.x += bf2f(m0[0]) * w0; acc.y += bf2f(m0[1]) * w0;
            acc.z += bf2f(m0[2]) * w0; acc.w += bf2f(m0[3]) * w0;
            acc.x += bf2f(m1[0]) * w1; acc.y += bf2f(m1[1]) * w1;
            acc.z += bf2f(m1[2]) * w1; acc.w += bf2f(m1[3]) * w1;
            acc.x += bf2f(m2[0]) * w2; acc.y += bf2f(m2[1]) * w2;
            acc.z += bf2f(m2[2]) * w2; acc.w += bf2f(m2[3]) * w2;
            acc.x += bf2f(m3[0]) * w3; acc.y += bf2f(m3[1]) * w3;
            acc.z += bf2f(m3[2]) * w3; acc.w += bf2f(m3[3]) * w3;
        }
        for (; j < n; ++j) {
            int s0 = __shfl(src, j); float w0 = __shfl(w, j);
            short4v m0 = *(const short4v*)(msg + ((size_t)s0 << 8) + (lane << 2));
            acc.x += bf2f(m0[0]) * w0; acc.y += bf2f(m0[1]) * w0;
            acc.z += bf2f(m0[2]) * w0; acc.w += bf2f(m0[3]) * w0;
        }
        i += n;
    }
}

__global__ __launch_bounds__(256) void gather_e(
    const short* __restrict__ msg,       // [NV][256] bf16
    const int* __restrict__ perm,
    const int* __restrict__ off, const int* __restrict__ rend,
    const int* __restrict__ pairs, const float* __restrict__ regw,
    const float* __restrict__ e_in, const float* __restrict__ reg_sum,
    float* __restrict__ out, short* __restrict__ out_bf)   // out_bf may be null
{
    int r    = (blockIdx.x << 2) + (threadIdx.x >> 6);
    int lane = threadIdx.x & 63;
    float4 acc = ((const float4*)(e_in + (size_t)r * HD))[lane];
    gather_core(msg, perm, pairs, regw, off[r], rend[r], lane, acc);
    float inv = 1.0f / reg_sum[r];
    acc.x *= inv; acc.y *= inv; acc.z *= inv; acc.w *= inv;
    ((float4*)(out + (size_t)r * HD))[lane] = acc;
    if (out_bf) {
        short4v s;
        s[0] = f2bf(acc.x); s[1] = f2bf(acc.y); s[2] = f2bf(acc.z); s[3] = f2bf(acc.w);
        *(short4v*)(out_bf + (size_t)r * HD + (lane << 2)) = s;
    }
}

__global__ __launch_bounds__(256) void gather_v(
    const short* __restrict__ msg,       // [NE][256] bf16
    const int* __restrict__ perm,
    const int* __restrict__ off, const int* __restrict__ rend,
    const int* __restrict__ pairs, const float* __restrict__ regw,
    const float* __restrict__ v_f32, const short* __restrict__ v_bf,  // v_bf may be null
    const float* __restrict__ n_w,
    const float* __restrict__ reg_sum, float* __restrict__ out)
{
    int r    = (blockIdx.x << 2) + (threadIdx.x >> 6);
    int lane = threadIdx.x & 63;
    float nw = n_w[r];
    float4 a;
    if (v_bf) {
        short4v b = *(const short4v*)(v_bf + (size_t)r * HD + (lane << 2));
        a.x = bf2f(b[0]); a.y = bf2f(b[1]); a.z = bf2f(b[2]); a.w = bf2f(b[3]);
    } else {
        a = ((const float4*)(v_f32 + (size_t)r * HD))[lane];
    }
    float4 acc; acc.x = a.x * nw; acc.y = a.y * nw; acc.z = a.z * nw; acc.w = a.w * nw;
    gather_core(msg, perm, pairs, regw, off[r], rend[r], lane, acc);
    float inv = 1.0f / reg_sum[r];
    acc.x *= inv; acc.y *= inv; acc.z *= inv; acc.w *= inv;
    ((float4*)(out + (size_t)r * HD))[lane] = acc;
}

extern "C" void kernel_launch(void* const* d_in, const int* in_sizes, int n_in,
                              void* d_out, int out_size, void* d_ws, size_t ws_size,
                              hipStream_t stream) {
    const float* v   = (const float*)d_in[0];
    const float* e   = (const float*)d_in[1];
    const float* W1  = (const float*)d_in[2];
    const float* b1  = (const float*)d_in[3];
    const float* W2  = (const float*)d_in[4];
    const float* b2  = (const float*)d_in[5];
    const float* n_weight     = (const float*)d_in[6];
    const float* e_weight     = (const float*)d_in[7];
    const float* n_reg_weight = (const float*)d_in[8];
    const float* e_reg_weight = (const float*)d_in[9];
    const float* e_reg_sum    = (const float*)d_in[10];
    const float* n_reg_sum    = (const float*)d_in[11];
    const int* pairs_v = (const int*)d_in[12];
    const int* eidx    = (const int*)d_in[13];
    const int* pairs_e = (const int*)d_in[14];
    const int* vidx    = (const int*)d_in[15];

    float* out      = (float*)d_out;
    float* v_region = out;
    float* e_region = out + (size_t)NV * HD;

    // --- workspace layout ---
    // mandatory (~30 MB): msg, perms, offsets, W_bf, counters
    // optional (+30.7 MB): v_bf (25.6 MB), e_bf (5.12 MB)
    char* ws = (char*)d_ws;
    size_t o = 0;
    short* msg     = (short*)(ws + o); o += (size_t)NV * HD * 2;        // 25.6 MB
    int*   perm_e  = (int*)(ws + o);   o += (size_t)NP * 4;             // 1.6 MB
    int*   perm_v  = (int*)(ws + o);   o += (size_t)NP * 4;             // 1.6 MB
    int*   off_e   = (int*)(ws + o);   o += (size_t)NE * 4;
    int*   cur_e   = (int*)(ws + o);   o += (size_t)NE * 4;
    int*   off_v   = (int*)(ws + o);   o += (size_t)NV * 4;
    int*   cur_v   = (int*)(ws + o);   o += (size_t)NV * 4;
    short* W_bf    = (short*)(ws + o); o += (size_t)2 * 65536 * 2;      // 256 KB
    // zeroed region (one memset): cnt_e | cnt_v | tot[2]
    int*   cnt_e   = (int*)(ws + o);   o += (size_t)NE * 4;
    int*   cnt_v   = (int*)(ws + o);   o += (size_t)NV * 4;
    int*   tot     = (int*)(ws + o);   o += 2 * 4;
    size_t o_opt = o;
    short* v_bf    = (short*)(ws + o_opt);
    short* e_bf    = (short*)(ws + o_opt + (size_t)NV * HD * 2);
    size_t need_full = o_opt + (size_t)NV * HD * 2 + (size_t)NE * HD * 2;
    const int full = (ws_size >= need_full);   // launch-invariant -> graph-safe

    // CSR build + conversions
    hipMemsetAsync(cnt_e, 0, (size_t)(NE + NV + 2) * 4, stream);
    prep_kernel<<<PREP_VBLK + PREP_WBLK + PREP_HBLK, 256, 0, stream>>>(
        v, W1, W2, eidx, vidx, full ? v_bf : (short*)msg /*unused*/, W_bf,
        cnt_e, cnt_v, full);
    assign_kernel<<<(VPAD + NV + 255) / 256, 256, 0, stream>>>(
        cnt_e, cnt_v, off_e, cur_e, off_v, cur_v, tot);
    fill_kernel<<<(NP + 255) / 256, 256, 0, stream>>>(
        eidx, vidx, cur_e, cur_v, perm_e, perm_v);

    // msg = bf16( relu(v @ W1^T + b1) * n_weight )
    gemm_rs<<<(NV + 63) / 64, 256, 0, stream>>>(
        full ? (const void*)v_bf : (const void*)v, full, W_bf, b1, n_weight, msg, NV);
    // e_out = (e + gather(msg)) / e_reg_sum   (+ bf16 copy when full)
    gather_e<<<NE / 4, 256, 0, stream>>>(msg, perm_e, off_e, cur_e,
        pairs_v, n_reg_weight, e, e_reg_sum, e_region, full ? e_bf : (short*)0);
    // msg = bf16( relu(e_out @ W2^T + b2) * e_weight )
    gemm_rs<<<(NE + 63) / 64, 256, 0, stream>>>(
        full ? (const void*)e_bf : (const void*)e_region, full, W_bf + 65536, b2, e_weight, msg, NE);
    // v_out = (v*n_weight + gather(msg)) / n_reg_sum
    gather_v<<<NV / 4, 256, 0, stream>>>(msg, perm_v, off_v, cur_v,
        pairs_e, e_reg_weight, v, full ? v_bf : (short*)0, n_weight, n_reg_sum, v_region);
}